// Round 1
// baseline (238.888 us; speedup 1.0000x reference)
//
#include <hip/hip_runtime.h>
#include <cstdint>

typedef uint16_t u16;
typedef __attribute__((ext_vector_type(8))) short bf16x8;
typedef __attribute__((ext_vector_type(4))) short bf16x4;
typedef __attribute__((ext_vector_type(4))) float f32x4;

// 0.125 * log2(e): folded into Q projection so softmax is exp2(s) directly.
#define QSCALE 0.18033688011112042f

struct Ptr3 { const float* a; const float* b; const float* c; };

__device__ __forceinline__ u16 f2bf(float x) {
  union { float f; uint32_t u; } v; v.f = x;
  uint32_t r = (v.u + 0x7fffu + ((v.u >> 16) & 1u)) >> 16;
  return (u16)r;
}

// packed f32x2 -> bf16x2 (low = a, high = b). gfx950 has a HW instruction.
#if __has_builtin(__builtin_amdgcn_cvt_pk_bf16_f32)
typedef __bf16 bf2_t __attribute__((ext_vector_type(2)));
__device__ __forceinline__ uint32_t pkbf(float a, float b) {
  bf2_t v = __builtin_amdgcn_cvt_pk_bf16_f32(a, b);
  uint32_t u;
  __builtin_memcpy(&u, &v, 4);
  return u;
}
#else
__device__ __forceinline__ uint32_t pkbf(float a, float b) {
  return (uint32_t)f2bf(a) | ((uint32_t)f2bf(b) << 16);
}
#endif

// async global->LDS, 16B per lane. LDS dest is wave-uniform base + lane*16.
__device__ __forceinline__ void async16(void* lds, const void* g) {
  __builtin_amdgcn_global_load_lds((const __attribute__((address_space(1))) void*)g,
                                   (__attribute__((address_space(3))) void*)lds, 16, 0, 0);
}

// -------- fused pre-pass: input casts (12288 blocks) + weight transposes ---
// bx<12288: f32->bf16 cast of q/k/v. bx>=12288: 1024 transpose blocks
// (768 for Wq/Wk/Wv -> wt[w][h*64+k][d], 256 for out_w (KxN) -> wto (NxK)).
__global__ __launch_bounds__(256) void k_prep(Ptr3 in, u16* __restrict__ out,
                                              Ptr3 w, const float* __restrict__ ow,
                                              u16* __restrict__ wt, u16* __restrict__ wto) {
  __shared__ u16 tile[64 * 65];
  const int t = threadIdx.x;
  const int bx = blockIdx.x;
  if (bx < 12288) {
    int z = bx >> 12;
    int i = (bx & 4095) * 256 + t;
    const float* p = z == 0 ? in.a : (z == 1 ? in.b : in.c);
    float4 v = ((const float4*)p)[i];
    uint2 o2;
    o2.x = pkbf(v.x, v.y);
    o2.y = pkbf(v.z, v.w);
    *(uint2*)(out + (long)z * 4194304 + (long)i * 4) = o2;
    return;
  }
  const int b2 = bx - 12288;
  const float* src;
  long in_base, out_base;
  int rstr, r0, c0;
  u16* outp;
  if (b2 < 768) {
    int z = b2 >> 4;
    r0 = (b2 & 15) * 64; c0 = 0;
    src = (z < 16) ? w.a : (z < 32 ? w.b : w.c);
    in_base = (long)(z & 15) * 65536;
    out_base = (long)z * 65536;
    rstr = 64; outp = wt;
  } else {
    int idx = b2 - 768;
    r0 = (idx >> 4) * 64; c0 = (idx & 15) * 64;
    src = ow; in_base = 0; out_base = 0;
    rstr = 1024; outp = wto;
  }
  for (int e = t; e < 4096; e += 256) {
    int rr = e >> 6, cc = e & 63;
    tile[rr * 65 + cc] = f2bf(src[in_base + (long)(r0 + rr) * rstr + c0 + cc]);
  }
  __syncthreads();
  for (int s = t; s < 512; s += 256) {
    int cc = s >> 3, r8 = (s & 7) << 3;
    bf16x8 p;
    #pragma unroll
    for (int j = 0; j < 8; ++j) p[j] = (short)tile[(r8 + j) * 65 + cc];
    *(bf16x8*)(outp + out_base + (long)(c0 + cc) * 1024 + r0 + r8) = p;
  }
}

// ---------------- fused QKV GEMM: 128x128 tile, BK=64, grid (8,32,3) -------
// async16 staging with XOR-chunk swizzle (LDS pos p of row holds global chunk
// p^(row&7); flat stride 64 -> 2-way banks = free, async16-compatible).
// BK=64 halves barrier count vs BK=32. z<2: C bf16 = (A*Bt^T)*scale.
// z==2: epilogue transposes tile via LDS (T overlays As/Bs - dead after
// K-loop) and writes Vt[bh][d][l] directly.
__global__ __launch_bounds__(256) void k_gemm_qkv(const u16* __restrict__ A0,
                                                  const u16* __restrict__ B0,
                                                  u16* __restrict__ C0,
                                                  u16* __restrict__ Vt, float scale0) {
  __shared__ __align__(16) u16 smem[16640];   // As[0:8192) Bs[8192:16384) T[0:16640)
  u16* As = smem;
  u16* Bs = smem + 8192;
  u16* T  = smem;                             // z==2 epilogue only (128 x 130)
  const int z = blockIdx.z;
  const u16* A = A0 + (long)z * 4194304;
  const u16* Bt = B0 + (long)z * 1048576;
  const int t = threadIdx.x, lane = t & 63, quad = lane >> 4, l16 = lane & 15;
  const int wave = t >> 6, wy = wave >> 1, wx = wave & 1;
  const int m0 = blockIdx.y * 128, n0 = blockIdx.x * 128;
  const int wbase = t & 192;
  f32x4 acc[4][4] = {};
  for (int k0 = 0; k0 < 1024; k0 += 64) {
    __syncthreads();
    #pragma unroll
    for (int i = 0; i < 4; ++i) {
      int sb = i * 256 + wbase;
      int s = sb + lane;
      int row = s >> 3, c = s & 7;
      int cs = c ^ (row & 7);              // source chunk for LDS pos c
      async16(As + sb * 8, A + (long)(m0 + row) * 1024 + k0 + cs * 8);
      async16(Bs + sb * 8, Bt + (long)(n0 + row) * 1024 + k0 + cs * 8);
    }
    __syncthreads();
    #pragma unroll
    for (int kk = 0; kk < 2; ++kk) {
      bf16x8 af[4], bfr[4];
      #pragma unroll
      for (int mt = 0; mt < 4; ++mt) {
        int row = wy * 64 + mt * 16 + l16;
        int pos = (kk * 4 + quad) ^ (row & 7);
        af[mt] = *(const bf16x8*)(As + row * 64 + pos * 8);
      }
      #pragma unroll
      for (int nt = 0; nt < 4; ++nt) {
        int row = wx * 64 + nt * 16 + l16;
        int pos = (kk * 4 + quad) ^ (row & 7);
        bfr[nt] = *(const bf16x8*)(Bs + row * 64 + pos * 8);
      }
      #pragma unroll
      for (int mt = 0; mt < 4; ++mt)
        #pragma unroll
        for (int nt = 0; nt < 4; ++nt)
          acc[mt][nt] = __builtin_amdgcn_mfma_f32_16x16x32_bf16(af[mt], bfr[nt], acc[mt][nt], 0, 0, 0);
    }
  }
  if (z < 2) {
    u16* C = C0 + (long)z * 4194304;
    const float scale = z ? 1.0f : scale0;
    #pragma unroll
    for (int mt = 0; mt < 4; ++mt)
      #pragma unroll
      for (int nt = 0; nt < 4; ++nt) {
        int col = n0 + wx * 64 + nt * 16 + l16;
        int row = m0 + wy * 64 + mt * 16 + quad * 4;
        uint32_t ua = pkbf(acc[mt][nt][0] * scale, acc[mt][nt][1] * scale);
        uint32_t ub = pkbf(acc[mt][nt][2] * scale, acc[mt][nt][3] * scale);
        C[(long)row * 1024 + col] = (u16)ua;
        C[(long)(row + 1) * 1024 + col] = (u16)(ua >> 16);
        C[(long)(row + 2) * 1024 + col] = (u16)ub;
        C[(long)(row + 3) * 1024 + col] = (u16)(ub >> 16);
      }
  } else {
    __syncthreads();  // all waves done reading As/Bs before T overlays them
    #pragma unroll
    for (int mt = 0; mt < 4; ++mt)
      #pragma unroll
      for (int nt = 0; nt < 4; ++nt) {
        int cc = wx * 64 + nt * 16 + l16;
        int rr = wy * 64 + mt * 16 + quad * 4;
        uint32_t ua = pkbf(acc[mt][nt][0], acc[mt][nt][1]);
        uint32_t ub = pkbf(acc[mt][nt][2], acc[mt][nt][3]);
        T[(rr + 0) * 130 + cc] = (u16)ua;
        T[(rr + 1) * 130 + cc] = (u16)(ua >> 16);
        T[(rr + 2) * 130 + cc] = (u16)ub;
        T[(rr + 3) * 130 + cc] = (u16)(ub >> 16);
      }
    __syncthreads();
    const int h0 = blockIdx.x * 2, bb = m0 >> 11, lb = m0 & 2047;
    #pragma unroll
    for (int i = 0; i < 8; ++i) {
      int s = t + i * 256;           // 0..2047 = 128 cols x 16 l-chunks
      int c = s >> 4, l0 = (s & 15) * 8;
      bf16x8 p;
      #pragma unroll
      for (int j = 0; j < 8; ++j) p[j] = (short)T[(l0 + j) * 130 + c];
      *(bf16x8*)(Vt + (long)(bb * 16 + h0 + (c >> 6)) * 131072 +
                 (long)(c & 63) * 2048 + lb + l0) = p;
    }
  }
}

// ---- out-proj GEMM: 128x64 tile, grid (16,32), async16, f32 out + bias ----
// (R8-verbatim)
__global__ __launch_bounds__(256) void k_gemm_out(const u16* __restrict__ A,
                                                  const u16* __restrict__ Bt,
                                                  float* __restrict__ C,
                                                  const float* __restrict__ bias) {
  __shared__ __align__(16) u16 As[128 * 32];
  __shared__ __align__(16) u16 Bs[64 * 32];
  const int t = threadIdx.x, lane = t & 63, quad = lane >> 4, l16 = lane & 15;
  const int wave = t >> 6;
  const int m0 = blockIdx.y * 128, n0 = blockIdx.x * 64;
  const int wbase = t & 192;
  f32x4 acc[2][4] = {};
  for (int k0 = 0; k0 < 1024; k0 += 32) {
    __syncthreads();
    #pragma unroll
    for (int i = 0; i < 2; ++i) {
      int sb = i * 256 + wbase;
      int s = sb + lane;
      int row = s >> 2, c = s & 3;
      async16(As + sb * 8, A + (long)(m0 + row) * 1024 + k0 + c * 8);
    }
    {
      int s = t;
      int row = s >> 2, c = s & 3;
      async16(Bs + wbase * 8, Bt + (long)(n0 + row) * 1024 + k0 + c * 8);
    }
    __syncthreads();
    bf16x8 af[2], bfr[4];
    #pragma unroll
    for (int mt = 0; mt < 2; ++mt)
      af[mt] = *(const bf16x8*)(As + (wave * 32 + mt * 16 + l16) * 32 + quad * 8);
    #pragma unroll
    for (int nt = 0; nt < 4; ++nt)
      bfr[nt] = *(const bf16x8*)(Bs + (nt * 16 + l16) * 32 + quad * 8);
    #pragma unroll
    for (int mt = 0; mt < 2; ++mt)
      #pragma unroll
      for (int nt = 0; nt < 4; ++nt)
        acc[mt][nt] = __builtin_amdgcn_mfma_f32_16x16x32_bf16(af[mt], bfr[nt], acc[mt][nt], 0, 0, 0);
  }
  #pragma unroll
  for (int mt = 0; mt < 2; ++mt)
    #pragma unroll
    for (int nt = 0; nt < 4; ++nt) {
      int col = n0 + nt * 16 + l16;
      #pragma unroll
      for (int r = 0; r < 4; ++r) {
        int row = m0 + wave * 32 + mt * 16 + quad * 4 + r;
        C[(long)row * 1024 + col] = acc[mt][nt][r] + bias[col];
      }
    }
}

// ---------------- flash attention (R4 schedule, q-tile 128, 2 blocks/CU) ---
// 512 threads, q-tile 128 (16 rows/wave). Grid 512 = 16 q-tiles x 32 bh ->
// 2 blocks/CU, 16 waves/CU (was 256 blocks = 1 block/CU, 25% occ ceiling).
// Loop schedule is the proven R4 winner (do NOT reschedule - R5/R6/R7 all
// regressed); this round ONLY halves the per-block q-tile so a co-resident
// block hides the per-kt barrier drain. K/V re-reads (x16 vs x8 per bh) stay
// in the per-XCD L2: same-bh blocks are blockIdx==bh (mod 32) -> same XCD
// (mod 8), 4 bh x 512KB = 2MB < 4MB L2.
__global__ __launch_bounds__(512, 4) void k_flash(const u16* __restrict__ Qp,
                                                  const u16* __restrict__ Kp,
                                                  const u16* __restrict__ Vt,
                                                  u16* __restrict__ ctx) {
  __shared__ __align__(16) u16 qs[9216];       // 18KB: Q stage (128x64) reused as P (8x16x72)
  __shared__ __align__(16) u16 ks[64 * 72];    // K tile, padded rows
  __shared__ __align__(16) u16 vs[64 * 72];    // V^T tile, padded rows
  const int t = threadIdx.x, lane = t & 63, quad = lane >> 4, l16 = lane & 15;
  const int wave = t >> 6;                      // 0..7
  const int bh = blockIdx.x & 31, b = bh >> 4, h = bh & 15;
  const int q0 = (blockIdx.x >> 5) * 128;
  const long gkbase = (long)b * 2097152 + h * 64;
  const long gvbase = (long)bh * 131072;
  const int srow = t >> 3, sc = t & 7;          // staging: row 0..63, 16B chunk 0..7

  // ---- startup: Q via async16 (XOR swizzle), K/V tile 0 via regs ----
  {
    long gq = (long)(b * 2048 + q0) * 1024 + h * 64;
    #pragma unroll
    for (int i = 0; i < 2; ++i) {
      int s = i * 512 + t;
      int row = s >> 3, pos = s & 7, c = pos ^ (row & 7);
      async16(qs + (long)s * 8, Qp + gq + (long)row * 1024 + c * 8);
    }
  }
  bf16x8 kreg = *(const bf16x8*)(Kp + gkbase + (long)srow * 1024 + sc * 8);
  bf16x8 vreg = *(const bf16x8*)(Vt + gvbase + (long)srow * 2048 + sc * 8);
  __syncthreads();  // Q visible

  bf16x8 qf[2];
  #pragma unroll
  for (int kh = 0; kh < 2; ++kh) {
    int m = wave * 16 + l16;
    int pos = (kh * 4 + quad) ^ (m & 7);
    qf[kh] = *(const bf16x8*)(qs + m * 64 + pos * 8);
  }
  *(bf16x8*)(ks + srow * 72 + sc * 8) = kreg;
  *(bf16x8*)(vs + srow * 72 + sc * 8) = vreg;
  __syncthreads();  // K/V tile 0 visible; all qf reads drained -> qs safe as P

  u16* pw = qs + wave * 1152;  // per-wave P tile: 16 q-rows x 72

  float lsum[4] = {};
  f32x4 o[4] = {};

  for (int kt = 0; kt < 32; ++kt) {
    // register prefetch of next K/V tile (in flight across this compute phase)
    if (kt < 31) {
      int kv0 = (kt + 1) * 64;
      kreg = *(const bf16x8*)(Kp + gkbase + (long)(kv0 + srow) * 1024 + sc * 8);
      vreg = *(const bf16x8*)(Vt + gvbase + kv0 + (long)srow * 2048 + sc * 8);
    }

    // K and V^T fragments (vector b128, <=2-way banks)
    bf16x8 kf[4][2], vf[4][2];
    #pragma unroll
    for (int nt = 0; nt < 4; ++nt)
      #pragma unroll
      for (int kh = 0; kh < 2; ++kh) {
        kf[nt][kh] = *(const bf16x8*)(ks + (nt * 16 + l16) * 72 + kh * 32 + quad * 8);
        vf[nt][kh] = *(const bf16x8*)(vs + (nt * 16 + l16) * 72 + kh * 32 + quad * 8);
      }

    // S(16x64) = Q @ K^T ; p = exp2(s); write P row-major [q][kv] to LDS
    #pragma unroll
    for (int nt = 0; nt < 4; ++nt) {
      f32x4 a = {};
      #pragma unroll
      for (int kh = 0; kh < 2; ++kh)
        a = __builtin_amdgcn_mfma_f32_16x16x32_bf16(qf[kh], kf[nt][kh], a, 0, 0, 0);
      float e0 = __builtin_amdgcn_exp2f(a[0]);
      float e1 = __builtin_amdgcn_exp2f(a[1]);
      float e2 = __builtin_amdgcn_exp2f(a[2]);
      float e3 = __builtin_amdgcn_exp2f(a[3]);
      lsum[0] += e0; lsum[1] += e1;
      lsum[2] += e2; lsum[3] += e3;
      uint32_t ua = pkbf(e0, e1), ub = pkbf(e2, e3);
      u16* pc = pw + (quad * 4) * 72 + nt * 16 + l16;
      pc[0]       = (u16)ua;
      pc[72]      = (u16)(ua >> 16);
      pc[144]     = (u16)ub;
      pc[216]     = (u16)(ub >> 16);
    }
    // O(16x64) += P @ V : A-frag = contiguous b128 rows of P
    #pragma unroll
    for (int kh = 0; kh < 2; ++kh) {
      bf16x8 pa = *(const bf16x8*)(pw + l16 * 72 + kh * 32 + quad * 8);
      #pragma unroll
      for (int nt = 0; nt < 4; ++nt)
        o[nt] = __builtin_amdgcn_mfma_f32_16x16x32_bf16(pa, vf[nt][kh], o[nt], 0, 0, 0);
    }

    __syncthreads();  // all waves done reading ks/vs (and prefetch drained)
    if (kt < 31) {
      *(bf16x8*)(ks + srow * 72 + sc * 8) = kreg;
      *(bf16x8*)(vs + srow * 72 + sc * 8) = vreg;
    }
    __syncthreads();  // next tile visible
  }

  // final l reduction across the 16 kv-lanes, then normalize + write
  #pragma unroll
  for (int r = 0; r < 4; ++r) {
    float l = lsum[r];
    #pragma unroll
    for (int d = 1; d < 16; d <<= 1) l += __shfl_xor(l, d);
    lsum[r] = 1.0f / l;
  }
  #pragma unroll
  for (int nt = 0; nt < 4; ++nt) {
    int q = q0 + wave * 16 + quad * 4;
    long idx = (long)(b * 2048 + q) * 1024 + h * 64 + nt * 16 + l16;
    uint32_t ua = pkbf(o[nt][0] * lsum[0], o[nt][1] * lsum[1]);
    uint32_t ub = pkbf(o[nt][2] * lsum[2], o[nt][3] * lsum[3]);
    ctx[idx]        = (u16)ua;
    ctx[idx + 1024] = (u16)(ua >> 16);
    ctx[idx + 2048] = (u16)ub;
    ctx[idx + 3072] = (u16)(ub >> 16);
  }
}

extern "C" void kernel_launch(void* const* d_in, const int* in_sizes, int n_in,
                              void* d_out, int out_size, void* d_ws, size_t ws_size,
                              hipStream_t stream) {
  const float* query = (const float*)d_in[0];
  const float* key   = (const float*)d_in[1];
  const float* value = (const float*)d_in[2];
  const float* Wq    = (const float*)d_in[3];
  const float* Wk    = (const float*)d_in[4];
  const float* Wv    = (const float*)d_in[5];
  const float* out_w = (const float*)d_in[6];
  const float* out_b = (const float*)d_in[7];
  // d_in[8] = coupling: unused — per-head scalar bias is softmax-invariant.
  float* out = (float*)d_out;

  char* ws = (char*)d_ws;
  size_t off = 0;
  auto alloc = [&](size_t bytes) {
    void* p = ws + off;
    off += (bytes + 255) & ~(size_t)255;
    return p;
  };
  // qb,kb,vb contiguous (k_prep cast z-stride); wtq..wtv contiguous
  // (k_prep transpose z-stride); Qp,Kp contiguous (k_gemm_qkv z<2 stride).
  u16* qb  = (u16*)alloc(4096L * 1024 * 2);
  u16* kb  = (u16*)alloc(4096L * 1024 * 2);
  u16* vb  = (u16*)alloc(4096L * 1024 * 2);
  u16* wtq = (u16*)alloc(1024L * 1024 * 2);
  u16* wtk = (u16*)alloc(1024L * 1024 * 2);
  u16* wtv = (u16*)alloc(1024L * 1024 * 2);
  u16* wto = (u16*)alloc(1024L * 1024 * 2);
  u16* Qp  = (u16*)alloc(4096L * 1024 * 2);
  u16* Kp  = (u16*)alloc(4096L * 1024 * 2);
  u16* Vtb = (u16*)alloc(4096L * 1024 * 2);
  u16* ctx = qb;  // reuse: query-bf16 dead after Q projection
  (void)kb; (void)vb; (void)wtk; (void)wtv; (void)Kp;

  // fused pre-pass: input casts + all weight transposes in one launch
  k_prep<<<13312, 256, 0, stream>>>(Ptr3{query, key, value}, qb,
                                    Ptr3{Wq, Wk, Wv}, out_w, wtq, wto);

  // fused Q,K,V projections; z==2 writes Vt[bh][d][l] directly
  k_gemm_qkv<<<dim3(8, 32, 3), 256, 0, stream>>>(qb, wtq, Qp, Vtb, QSCALE);

  // attention: grid 512 = 16 q-tiles x 32 bh, bh in low 5 bits for XCD affinity
  k_flash<<<512, 512, 0, stream>>>(Qp, Kp, Vtb, ctx);

  // output projection + bias -> f32
  k_gemm_out<<<dim3(16, 32), 256, 0, stream>>>(ctx, wto, out, out_b);
}

// Round 2
// 231.155 us; speedup vs baseline: 1.0335x; 1.0335x over previous
//
#include <hip/hip_runtime.h>
#include <cstdint>

typedef uint16_t u16;
typedef __attribute__((ext_vector_type(8))) short bf16x8;
typedef __attribute__((ext_vector_type(4))) short bf16x4;
typedef __attribute__((ext_vector_type(4))) float f32x4;

// 0.125 * log2(e): folded into Q projection so softmax is exp2(s) directly.
#define QSCALE 0.18033688011112042f

struct Ptr3 { const float* a; const float* b; const float* c; };

__device__ __forceinline__ u16 f2bf(float x) {
  union { float f; uint32_t u; } v; v.f = x;
  uint32_t r = (v.u + 0x7fffu + ((v.u >> 16) & 1u)) >> 16;
  return (u16)r;
}

// packed f32x2 -> bf16x2 (low = a, high = b). gfx950 has a HW instruction.
#if __has_builtin(__builtin_amdgcn_cvt_pk_bf16_f32)
typedef __bf16 bf2_t __attribute__((ext_vector_type(2)));
__device__ __forceinline__ uint32_t pkbf(float a, float b) {
  bf2_t v = __builtin_amdgcn_cvt_pk_bf16_f32(a, b);
  uint32_t u;
  __builtin_memcpy(&u, &v, 4);
  return u;
}
#else
__device__ __forceinline__ uint32_t pkbf(float a, float b) {
  return (uint32_t)f2bf(a) | ((uint32_t)f2bf(b) << 16);
}
#endif

// async global->LDS, 16B per lane. LDS dest is wave-uniform base + lane*16.
__device__ __forceinline__ void async16(void* lds, const void* g) {
  __builtin_amdgcn_global_load_lds((const __attribute__((address_space(1))) void*)g,
                                   (__attribute__((address_space(3))) void*)lds, 16, 0, 0);
}

// -------- fused pre-pass: input casts (12288 blocks) + weight transposes ---
// bx<12288: f32->bf16 cast of q/k/v. bx>=12288: 1024 transpose blocks
// (768 for Wq/Wk/Wv -> wt[w][h*64+k][d], 256 for out_w (KxN) -> wto (NxK)).
__global__ __launch_bounds__(256) void k_prep(Ptr3 in, u16* __restrict__ out,
                                              Ptr3 w, const float* __restrict__ ow,
                                              u16* __restrict__ wt, u16* __restrict__ wto) {
  __shared__ u16 tile[64 * 65];
  const int t = threadIdx.x;
  const int bx = blockIdx.x;
  if (bx < 12288) {
    int z = bx >> 12;
    int i = (bx & 4095) * 256 + t;
    const float* p = z == 0 ? in.a : (z == 1 ? in.b : in.c);
    float4 v = ((const float4*)p)[i];
    uint2 o2;
    o2.x = pkbf(v.x, v.y);
    o2.y = pkbf(v.z, v.w);
    *(uint2*)(out + (long)z * 4194304 + (long)i * 4) = o2;
    return;
  }
  const int b2 = bx - 12288;
  const float* src;
  long in_base, out_base;
  int rstr, r0, c0;
  u16* outp;
  if (b2 < 768) {
    int z = b2 >> 4;
    r0 = (b2 & 15) * 64; c0 = 0;
    src = (z < 16) ? w.a : (z < 32 ? w.b : w.c);
    in_base = (long)(z & 15) * 65536;
    out_base = (long)z * 65536;
    rstr = 64; outp = wt;
  } else {
    int idx = b2 - 768;
    r0 = (idx >> 4) * 64; c0 = (idx & 15) * 64;
    src = ow; in_base = 0; out_base = 0;
    rstr = 1024; outp = wto;
  }
  for (int e = t; e < 4096; e += 256) {
    int rr = e >> 6, cc = e & 63;
    tile[rr * 65 + cc] = f2bf(src[in_base + (long)(r0 + rr) * rstr + c0 + cc]);
  }
  __syncthreads();
  for (int s = t; s < 512; s += 256) {
    int cc = s >> 3, r8 = (s & 7) << 3;
    bf16x8 p;
    #pragma unroll
    for (int j = 0; j < 8; ++j) p[j] = (short)tile[(r8 + j) * 65 + cc];
    *(bf16x8*)(outp + out_base + (long)(c0 + cc) * 1024 + r0 + r8) = p;
  }
}

// ---------------- fused QKV GEMM: 128x128 tile, BK=64, grid (8,32,3) -------
// async16 staging with XOR-chunk swizzle (LDS pos p of row holds global chunk
// p^(row&7); flat stride 64 -> 2-way banks = free, async16-compatible).
// BK=64 halves barrier count vs BK=32. z<2: C bf16 = (A*Bt^T)*scale.
// z==2: epilogue transposes tile via LDS (T overlays As/Bs - dead after
// K-loop) and writes Vt[bh][d][l] directly.
__global__ __launch_bounds__(256) void k_gemm_qkv(const u16* __restrict__ A0,
                                                  const u16* __restrict__ B0,
                                                  u16* __restrict__ C0,
                                                  u16* __restrict__ Vt, float scale0) {
  __shared__ __align__(16) u16 smem[16640];   // As[0:8192) Bs[8192:16384) T[0:16640)
  u16* As = smem;
  u16* Bs = smem + 8192;
  u16* T  = smem;                             // z==2 epilogue only (128 x 130)
  const int z = blockIdx.z;
  const u16* A = A0 + (long)z * 4194304;
  const u16* Bt = B0 + (long)z * 1048576;
  const int t = threadIdx.x, lane = t & 63, quad = lane >> 4, l16 = lane & 15;
  const int wave = t >> 6, wy = wave >> 1, wx = wave & 1;
  const int m0 = blockIdx.y * 128, n0 = blockIdx.x * 128;
  const int wbase = t & 192;
  f32x4 acc[4][4] = {};
  for (int k0 = 0; k0 < 1024; k0 += 64) {
    __syncthreads();
    #pragma unroll
    for (int i = 0; i < 4; ++i) {
      int sb = i * 256 + wbase;
      int s = sb + lane;
      int row = s >> 3, c = s & 7;
      int cs = c ^ (row & 7);              // source chunk for LDS pos c
      async16(As + sb * 8, A + (long)(m0 + row) * 1024 + k0 + cs * 8);
      async16(Bs + sb * 8, Bt + (long)(n0 + row) * 1024 + k0 + cs * 8);
    }
    __syncthreads();
    #pragma unroll
    for (int kk = 0; kk < 2; ++kk) {
      bf16x8 af[4], bfr[4];
      #pragma unroll
      for (int mt = 0; mt < 4; ++mt) {
        int row = wy * 64 + mt * 16 + l16;
        int pos = (kk * 4 + quad) ^ (row & 7);
        af[mt] = *(const bf16x8*)(As + row * 64 + pos * 8);
      }
      #pragma unroll
      for (int nt = 0; nt < 4; ++nt) {
        int row = wx * 64 + nt * 16 + l16;
        int pos = (kk * 4 + quad) ^ (row & 7);
        bfr[nt] = *(const bf16x8*)(Bs + row * 64 + pos * 8);
      }
      #pragma unroll
      for (int mt = 0; mt < 4; ++mt)
        #pragma unroll
        for (int nt = 0; nt < 4; ++nt)
          acc[mt][nt] = __builtin_amdgcn_mfma_f32_16x16x32_bf16(af[mt], bfr[nt], acc[mt][nt], 0, 0, 0);
    }
  }
  if (z < 2) {
    u16* C = C0 + (long)z * 4194304;
    const float scale = z ? 1.0f : scale0;
    #pragma unroll
    for (int mt = 0; mt < 4; ++mt)
      #pragma unroll
      for (int nt = 0; nt < 4; ++nt) {
        int col = n0 + wx * 64 + nt * 16 + l16;
        int row = m0 + wy * 64 + mt * 16 + quad * 4;
        uint32_t ua = pkbf(acc[mt][nt][0] * scale, acc[mt][nt][1] * scale);
        uint32_t ub = pkbf(acc[mt][nt][2] * scale, acc[mt][nt][3] * scale);
        C[(long)row * 1024 + col] = (u16)ua;
        C[(long)(row + 1) * 1024 + col] = (u16)(ua >> 16);
        C[(long)(row + 2) * 1024 + col] = (u16)ub;
        C[(long)(row + 3) * 1024 + col] = (u16)(ub >> 16);
      }
  } else {
    __syncthreads();  // all waves done reading As/Bs before T overlays them
    #pragma unroll
    for (int mt = 0; mt < 4; ++mt)
      #pragma unroll
      for (int nt = 0; nt < 4; ++nt) {
        int cc = wx * 64 + nt * 16 + l16;
        int rr = wy * 64 + mt * 16 + quad * 4;
        uint32_t ua = pkbf(acc[mt][nt][0], acc[mt][nt][1]);
        uint32_t ub = pkbf(acc[mt][nt][2], acc[mt][nt][3]);
        T[(rr + 0) * 130 + cc] = (u16)ua;
        T[(rr + 1) * 130 + cc] = (u16)(ua >> 16);
        T[(rr + 2) * 130 + cc] = (u16)ub;
        T[(rr + 3) * 130 + cc] = (u16)(ub >> 16);
      }
    __syncthreads();
    const int h0 = blockIdx.x * 2, bb = m0 >> 11, lb = m0 & 2047;
    #pragma unroll
    for (int i = 0; i < 8; ++i) {
      int s = t + i * 256;           // 0..2047 = 128 cols x 16 l-chunks
      int c = s >> 4, l0 = (s & 15) * 8;
      bf16x8 p;
      #pragma unroll
      for (int j = 0; j < 8; ++j) p[j] = (short)T[(l0 + j) * 130 + c];
      *(bf16x8*)(Vt + (long)(bb * 16 + h0 + (c >> 6)) * 131072 +
                 (long)(c & 63) * 2048 + lb + l0) = p;
    }
  }
}

// ---- out-proj GEMM: 128x64 tile, grid (16,32), async16, f32 out + bias ----
// (R8-verbatim)
__global__ __launch_bounds__(256) void k_gemm_out(const u16* __restrict__ A,
                                                  const u16* __restrict__ Bt,
                                                  float* __restrict__ C,
                                                  const float* __restrict__ bias) {
  __shared__ __align__(16) u16 As[128 * 32];
  __shared__ __align__(16) u16 Bs[64 * 32];
  const int t = threadIdx.x, lane = t & 63, quad = lane >> 4, l16 = lane & 15;
  const int wave = t >> 6;
  const int m0 = blockIdx.y * 128, n0 = blockIdx.x * 64;
  const int wbase = t & 192;
  f32x4 acc[2][4] = {};
  for (int k0 = 0; k0 < 1024; k0 += 32) {
    __syncthreads();
    #pragma unroll
    for (int i = 0; i < 2; ++i) {
      int sb = i * 256 + wbase;
      int s = sb + lane;
      int row = s >> 2, c = s & 3;
      async16(As + sb * 8, A + (long)(m0 + row) * 1024 + k0 + c * 8);
    }
    {
      int s = t;
      int row = s >> 2, c = s & 3;
      async16(Bs + wbase * 8, Bt + (long)(n0 + row) * 1024 + k0 + c * 8);
    }
    __syncthreads();
    bf16x8 af[2], bfr[4];
    #pragma unroll
    for (int mt = 0; mt < 2; ++mt)
      af[mt] = *(const bf16x8*)(As + (wave * 32 + mt * 16 + l16) * 32 + quad * 8);
    #pragma unroll
    for (int nt = 0; nt < 4; ++nt)
      bfr[nt] = *(const bf16x8*)(Bs + (nt * 16 + l16) * 32 + quad * 8);
    #pragma unroll
    for (int mt = 0; mt < 2; ++mt)
      #pragma unroll
      for (int nt = 0; nt < 4; ++nt)
        acc[mt][nt] = __builtin_amdgcn_mfma_f32_16x16x32_bf16(af[mt], bfr[nt], acc[mt][nt], 0, 0, 0);
  }
  #pragma unroll
  for (int mt = 0; mt < 2; ++mt)
    #pragma unroll
    for (int nt = 0; nt < 4; ++nt) {
      int col = n0 + nt * 16 + l16;
      #pragma unroll
      for (int r = 0; r < 4; ++r) {
        int row = m0 + wave * 32 + mt * 16 + quad * 4 + r;
        C[(long)row * 1024 + col] = acc[mt][nt][r] + bias[col];
      }
    }
}

// ---------------- flash attention (R4 schedule, q-tile 256, swapped QK) ----
// 512 threads, q-tile 256 (32 rows/wave), grid 256 = 1 block/CU — R1 showed
// 2 blocks/CU regresses (per-wave K/V LDS reads don't shrink with q-tile, so
// MFMA-per-LDS-byte halves; conflicts doubled). Loop/barrier schedule is the
// proven R4 winner (do NOT reschedule — R5/R6/R7 regressed).
// THIS round's change (dataflow only, schedule untouched): QK^T computed with
// SWAPPED operands -> S^T. C-layout (col=lane&15, row=quad*4+reg) then gives
// each lane 4 CONSECUTIVE kv values of ONE q-row (q=l16), so:
//  - P-store per nt = one ds_write_b64 of 2 packed dwords (was 4 ds_write_b16
//    + 2 v_lshrrev): -24 LDS insts, -16 VALU insts per wave per kt.
//  - lsum collapses to one scalar per lane (all regs same q); final reduce is
//    2 shfl_xor over quads + 4 shfl to redistribute 1/l to output rows.
// P LDS layout ([q][kv], stride 72) and the PV read path are byte-identical.
__global__ __launch_bounds__(512, 2) void k_flash(const u16* __restrict__ Qp,
                                                  const u16* __restrict__ Kp,
                                                  const u16* __restrict__ Vt,
                                                  u16* __restrict__ ctx) {
  __shared__ __align__(16) u16 qs[256 * 64];   // 32KB Q stage; reused as P buffers
  __shared__ __align__(16) u16 ks[64 * 72];    // K tile, padded rows
  __shared__ __align__(16) u16 vs[64 * 72];    // V^T tile, padded rows
  const int t = threadIdx.x, lane = t & 63, quad = lane >> 4, l16 = lane & 15;
  const int wave = t >> 6;                      // 0..7
  const int bh = blockIdx.x & 31, b = bh >> 4, h = bh & 15;
  const int q0 = (blockIdx.x >> 5) * 256;
  const long gkbase = (long)b * 2097152 + h * 64;
  const long gvbase = (long)bh * 131072;
  const int srow = t >> 3, sc = t & 7;          // staging: row 0..63, 16B chunk 0..7

  // ---- startup: Q via async16 (XOR swizzle), K/V tile 0 via regs ----
  {
    long gq = (long)(b * 2048 + q0) * 1024 + h * 64;
    #pragma unroll
    for (int i = 0; i < 4; ++i) {
      int s = i * 512 + t;
      int row = s >> 3, pos = s & 7, c = pos ^ (row & 7);
      async16(qs + (long)s * 8, Qp + gq + (long)row * 1024 + c * 8);
    }
  }
  bf16x8 kreg = *(const bf16x8*)(Kp + gkbase + (long)srow * 1024 + sc * 8);
  bf16x8 vreg = *(const bf16x8*)(Vt + gvbase + (long)srow * 2048 + sc * 8);
  __syncthreads();  // Q visible

  bf16x8 qf[2][2];
  #pragma unroll
  for (int msub = 0; msub < 2; ++msub)
    #pragma unroll
    for (int kh = 0; kh < 2; ++kh) {
      int m = wave * 32 + msub * 16 + l16;
      int pos = (kh * 4 + quad) ^ (m & 7);
      qf[msub][kh] = *(const bf16x8*)(qs + m * 64 + pos * 8);
    }
  *(bf16x8*)(ks + srow * 72 + sc * 8) = kreg;
  *(bf16x8*)(vs + srow * 72 + sc * 8) = vreg;
  __syncthreads();  // K/V tile 0 visible; all qf reads drained -> qs safe as P

  u16* pw = qs + wave * 1152;  // per-wave P tile: 16 q-rows x 72 (one msub at a time)

  float ls[2] = {};
  f32x4 o[2][4] = {};

  for (int kt = 0; kt < 32; ++kt) {
    // register prefetch of next K/V tile (in flight across this compute phase)
    if (kt < 31) {
      int kv0 = (kt + 1) * 64;
      kreg = *(const bf16x8*)(Kp + gkbase + (long)(kv0 + srow) * 1024 + sc * 8);
      vreg = *(const bf16x8*)(Vt + gvbase + kv0 + (long)srow * 2048 + sc * 8);
    }

    // K and V^T fragments (vector b128, <=2-way banks)
    bf16x8 kf[4][2], vf[4][2];
    #pragma unroll
    for (int nt = 0; nt < 4; ++nt)
      #pragma unroll
      for (int kh = 0; kh < 2; ++kh) {
        kf[nt][kh] = *(const bf16x8*)(ks + (nt * 16 + l16) * 72 + kh * 32 + quad * 8);
        vf[nt][kh] = *(const bf16x8*)(vs + (nt * 16 + l16) * 72 + kh * 32 + quad * 8);
      }

    #pragma unroll
    for (int msub = 0; msub < 2; ++msub) {
      // S^T(64x16) = K @ Q^T ; lane holds S[q=l16][kv=nt*16+quad*4+r].
      // p = exp2(s); one b64 store per nt -> P[q][kv] row-major in LDS.
      #pragma unroll
      for (int nt = 0; nt < 4; ++nt) {
        f32x4 a = {};
        #pragma unroll
        for (int kh = 0; kh < 2; ++kh)
          a = __builtin_amdgcn_mfma_f32_16x16x32_bf16(kf[nt][kh], qf[msub][kh], a, 0, 0, 0);
        float e0 = __builtin_amdgcn_exp2f(a[0]);
        float e1 = __builtin_amdgcn_exp2f(a[1]);
        float e2 = __builtin_amdgcn_exp2f(a[2]);
        float e3 = __builtin_amdgcn_exp2f(a[3]);
        ls[msub] += (e0 + e1) + (e2 + e3);
        uint2 w;
        w.x = pkbf(e0, e1);
        w.y = pkbf(e2, e3);
        *(uint2*)(pw + l16 * 72 + nt * 16 + quad * 4) = w;
      }
      // O(16x64) += P @ V : A-frag = contiguous b128 rows of P (unchanged)
      #pragma unroll
      for (int kh = 0; kh < 2; ++kh) {
        bf16x8 pa = *(const bf16x8*)(pw + l16 * 72 + kh * 32 + quad * 8);
        #pragma unroll
        for (int nt = 0; nt < 4; ++nt)
          o[msub][nt] = __builtin_amdgcn_mfma_f32_16x16x32_bf16(pa, vf[nt][kh], o[msub][nt], 0, 0, 0);
      }
    }

    __syncthreads();  // all waves done reading ks/vs (and prefetch drained)
    if (kt < 31) {
      *(bf16x8*)(ks + srow * 72 + sc * 8) = kreg;
      *(bf16x8*)(vs + srow * 72 + sc * 8) = vreg;
    }
    __syncthreads();  // next tile visible
  }

  // final l: reduce over the 4 quads (each lane holds partial for q=l16),
  // reciprocal, then shuffle 1/l to the lanes holding output rows quad*4+r.
  #pragma unroll
  for (int msub = 0; msub < 2; ++msub) {
    float l = ls[msub];
    l += __shfl_xor(l, 16);
    l += __shfl_xor(l, 32);
    float linv = 1.0f / l;                 // valid for q = l16 on every lane
    float li0 = __shfl(linv, quad * 4 + 0);
    float li1 = __shfl(linv, quad * 4 + 1);
    float li2 = __shfl(linv, quad * 4 + 2);
    float li3 = __shfl(linv, quad * 4 + 3);
    #pragma unroll
    for (int nt = 0; nt < 4; ++nt) {
      int q = q0 + wave * 32 + msub * 16 + quad * 4;
      long idx = (long)(b * 2048 + q) * 1024 + h * 64 + nt * 16 + l16;
      uint32_t ua = pkbf(o[msub][nt][0] * li0, o[msub][nt][1] * li1);
      uint32_t ub = pkbf(o[msub][nt][2] * li2, o[msub][nt][3] * li3);
      ctx[idx]        = (u16)ua;
      ctx[idx + 1024] = (u16)(ua >> 16);
      ctx[idx + 2048] = (u16)ub;
      ctx[idx + 3072] = (u16)(ub >> 16);
    }
  }
}

extern "C" void kernel_launch(void* const* d_in, const int* in_sizes, int n_in,
                              void* d_out, int out_size, void* d_ws, size_t ws_size,
                              hipStream_t stream) {
  const float* query = (const float*)d_in[0];
  const float* key   = (const float*)d_in[1];
  const float* value = (const float*)d_in[2];
  const float* Wq    = (const float*)d_in[3];
  const float* Wk    = (const float*)d_in[4];
  const float* Wv    = (const float*)d_in[5];
  const float* out_w = (const float*)d_in[6];
  const float* out_b = (const float*)d_in[7];
  // d_in[8] = coupling: unused — per-head scalar bias is softmax-invariant.
  float* out = (float*)d_out;

  char* ws = (char*)d_ws;
  size_t off = 0;
  auto alloc = [&](size_t bytes) {
    void* p = ws + off;
    off += (bytes + 255) & ~(size_t)255;
    return p;
  };
  // qb,kb,vb contiguous (k_prep cast z-stride); wtq..wtv contiguous
  // (k_prep transpose z-stride); Qp,Kp contiguous (k_gemm_qkv z<2 stride).
  u16* qb  = (u16*)alloc(4096L * 1024 * 2);
  u16* kb  = (u16*)alloc(4096L * 1024 * 2);
  u16* vb  = (u16*)alloc(4096L * 1024 * 2);
  u16* wtq = (u16*)alloc(1024L * 1024 * 2);
  u16* wtk = (u16*)alloc(1024L * 1024 * 2);
  u16* wtv = (u16*)alloc(1024L * 1024 * 2);
  u16* wto = (u16*)alloc(1024L * 1024 * 2);
  u16* Qp  = (u16*)alloc(4096L * 1024 * 2);
  u16* Kp  = (u16*)alloc(4096L * 1024 * 2);
  u16* Vtb = (u16*)alloc(4096L * 1024 * 2);
  u16* ctx = qb;  // reuse: query-bf16 dead after Q projection
  (void)kb; (void)vb; (void)wtk; (void)wtv; (void)Kp;

  // fused pre-pass: input casts + all weight transposes in one launch
  k_prep<<<13312, 256, 0, stream>>>(Ptr3{query, key, value}, qb,
                                    Ptr3{Wq, Wk, Wv}, out_w, wtq, wto);

  // fused Q,K,V projections; z==2 writes Vt[bh][d][l] directly
  k_gemm_qkv<<<dim3(8, 32, 3), 256, 0, stream>>>(qb, wtq, Qp, Vtb, QSCALE);

  // attention: grid 256 = 8 q-tiles x 32 bh, bh in low 5 bits for XCD affinity
  k_flash<<<256, 512, 0, stream>>>(Qp, Kp, Vtb, ctx);

  // output projection + bias -> f32
  k_gemm_out<<<dim3(16, 32), 256, 0, stream>>>(ctx, wto, out, out_b);
}

// Round 3
// 229.698 us; speedup vs baseline: 1.0400x; 1.0063x over previous
//
#include <hip/hip_runtime.h>
#include <cstdint>

typedef uint16_t u16;
typedef __attribute__((ext_vector_type(8))) short bf16x8;
typedef __attribute__((ext_vector_type(4))) short bf16x4;
typedef __attribute__((ext_vector_type(4))) float f32x4;

// 0.125 * log2(e): folded into Q projection so softmax is exp2(s) directly.
#define QSCALE 0.18033688011112042f

struct Ptr3 { const float* a; const float* b; const float* c; };

__device__ __forceinline__ u16 f2bf(float x) {
  union { float f; uint32_t u; } v; v.f = x;
  uint32_t r = (v.u + 0x7fffu + ((v.u >> 16) & 1u)) >> 16;
  return (u16)r;
}

// packed f32x2 -> bf16x2 (low = a, high = b). gfx950 has a HW instruction.
#if __has_builtin(__builtin_amdgcn_cvt_pk_bf16_f32)
typedef __bf16 bf2_t __attribute__((ext_vector_type(2)));
__device__ __forceinline__ uint32_t pkbf(float a, float b) {
  bf2_t v = __builtin_amdgcn_cvt_pk_bf16_f32(a, b);
  uint32_t u;
  __builtin_memcpy(&u, &v, 4);
  return u;
}
#else
__device__ __forceinline__ uint32_t pkbf(float a, float b) {
  return (uint32_t)f2bf(a) | ((uint32_t)f2bf(b) << 16);
}
#endif

// async global->LDS, 16B per lane. LDS dest is wave-uniform base + lane*16.
__device__ __forceinline__ void async16(void* lds, const void* g) {
  __builtin_amdgcn_global_load_lds((const __attribute__((address_space(1))) void*)g,
                                   (__attribute__((address_space(3))) void*)lds, 16, 0, 0);
}

// -------- fused pre-pass: input casts (12288 blocks) + weight transposes ---
// bx<12288: f32->bf16 cast of q/k/v. bx>=12288: 1024 transpose blocks
// (768 for Wq/Wk/Wv -> wt[w][h*64+k][d], 256 for out_w (KxN) -> wto (NxK)).
__global__ __launch_bounds__(256) void k_prep(Ptr3 in, u16* __restrict__ out,
                                              Ptr3 w, const float* __restrict__ ow,
                                              u16* __restrict__ wt, u16* __restrict__ wto) {
  __shared__ u16 tile[64 * 65];
  const int t = threadIdx.x;
  const int bx = blockIdx.x;
  if (bx < 12288) {
    int z = bx >> 12;
    int i = (bx & 4095) * 256 + t;
    const float* p = z == 0 ? in.a : (z == 1 ? in.b : in.c);
    float4 v = ((const float4*)p)[i];
    uint2 o2;
    o2.x = pkbf(v.x, v.y);
    o2.y = pkbf(v.z, v.w);
    *(uint2*)(out + (long)z * 4194304 + (long)i * 4) = o2;
    return;
  }
  const int b2 = bx - 12288;
  const float* src;
  long in_base, out_base;
  int rstr, r0, c0;
  u16* outp;
  if (b2 < 768) {
    int z = b2 >> 4;
    r0 = (b2 & 15) * 64; c0 = 0;
    src = (z < 16) ? w.a : (z < 32 ? w.b : w.c);
    in_base = (long)(z & 15) * 65536;
    out_base = (long)z * 65536;
    rstr = 64; outp = wt;
  } else {
    int idx = b2 - 768;
    r0 = (idx >> 4) * 64; c0 = (idx & 15) * 64;
    src = ow; in_base = 0; out_base = 0;
    rstr = 1024; outp = wto;
  }
  for (int e = t; e < 4096; e += 256) {
    int rr = e >> 6, cc = e & 63;
    tile[rr * 65 + cc] = f2bf(src[in_base + (long)(r0 + rr) * rstr + c0 + cc]);
  }
  __syncthreads();
  for (int s = t; s < 512; s += 256) {
    int cc = s >> 3, r8 = (s & 7) << 3;
    bf16x8 p;
    #pragma unroll
    for (int j = 0; j < 8; ++j) p[j] = (short)tile[(r8 + j) * 65 + cc];
    *(bf16x8*)(outp + out_base + (long)(c0 + cc) * 1024 + r0 + r8) = p;
  }
}

// ---------------- fused QKV GEMM: 128x128 tile, BK=64, grid (8,32,3) -------
// async16 staging with XOR-chunk swizzle (LDS pos p of row holds global chunk
// p^(row&7); flat stride 64 -> 2-way banks = free, async16-compatible).
// BK=64 halves barrier count vs BK=32. z<2: C bf16 = (A*Bt^T)*scale.
// z==2: epilogue transposes tile via LDS (T overlays As/Bs - dead after
// K-loop) and writes Vt[bh][d][l] directly.
__global__ __launch_bounds__(256) void k_gemm_qkv(const u16* __restrict__ A0,
                                                  const u16* __restrict__ B0,
                                                  u16* __restrict__ C0,
                                                  u16* __restrict__ Vt, float scale0) {
  __shared__ __align__(16) u16 smem[16640];   // As[0:8192) Bs[8192:16384) T[0:16640)
  u16* As = smem;
  u16* Bs = smem + 8192;
  u16* T  = smem;                             // z==2 epilogue only (128 x 130)
  const int z = blockIdx.z;
  const u16* A = A0 + (long)z * 4194304;
  const u16* Bt = B0 + (long)z * 1048576;
  const int t = threadIdx.x, lane = t & 63, quad = lane >> 4, l16 = lane & 15;
  const int wave = t >> 6, wy = wave >> 1, wx = wave & 1;
  const int m0 = blockIdx.y * 128, n0 = blockIdx.x * 128;
  const int wbase = t & 192;
  f32x4 acc[4][4] = {};
  for (int k0 = 0; k0 < 1024; k0 += 64) {
    __syncthreads();
    #pragma unroll
    for (int i = 0; i < 4; ++i) {
      int sb = i * 256 + wbase;
      int s = sb + lane;
      int row = s >> 3, c = s & 7;
      int cs = c ^ (row & 7);              // source chunk for LDS pos c
      async16(As + sb * 8, A + (long)(m0 + row) * 1024 + k0 + cs * 8);
      async16(Bs + sb * 8, Bt + (long)(n0 + row) * 1024 + k0 + cs * 8);
    }
    __syncthreads();
    #pragma unroll
    for (int kk = 0; kk < 2; ++kk) {
      bf16x8 af[4], bfr[4];
      #pragma unroll
      for (int mt = 0; mt < 4; ++mt) {
        int row = wy * 64 + mt * 16 + l16;
        int pos = (kk * 4 + quad) ^ (row & 7);
        af[mt] = *(const bf16x8*)(As + row * 64 + pos * 8);
      }
      #pragma unroll
      for (int nt = 0; nt < 4; ++nt) {
        int row = wx * 64 + nt * 16 + l16;
        int pos = (kk * 4 + quad) ^ (row & 7);
        bfr[nt] = *(const bf16x8*)(Bs + row * 64 + pos * 8);
      }
      #pragma unroll
      for (int mt = 0; mt < 4; ++mt)
        #pragma unroll
        for (int nt = 0; nt < 4; ++nt)
          acc[mt][nt] = __builtin_amdgcn_mfma_f32_16x16x32_bf16(af[mt], bfr[nt], acc[mt][nt], 0, 0, 0);
    }
  }
  if (z < 2) {
    u16* C = C0 + (long)z * 4194304;
    const float scale = z ? 1.0f : scale0;
    #pragma unroll
    for (int mt = 0; mt < 4; ++mt)
      #pragma unroll
      for (int nt = 0; nt < 4; ++nt) {
        int col = n0 + wx * 64 + nt * 16 + l16;
        int row = m0 + wy * 64 + mt * 16 + quad * 4;
        uint32_t ua = pkbf(acc[mt][nt][0] * scale, acc[mt][nt][1] * scale);
        uint32_t ub = pkbf(acc[mt][nt][2] * scale, acc[mt][nt][3] * scale);
        C[(long)row * 1024 + col] = (u16)ua;
        C[(long)(row + 1) * 1024 + col] = (u16)(ua >> 16);
        C[(long)(row + 2) * 1024 + col] = (u16)ub;
        C[(long)(row + 3) * 1024 + col] = (u16)(ub >> 16);
      }
  } else {
    __syncthreads();  // all waves done reading As/Bs before T overlays them
    #pragma unroll
    for (int mt = 0; mt < 4; ++mt)
      #pragma unroll
      for (int nt = 0; nt < 4; ++nt) {
        int cc = wx * 64 + nt * 16 + l16;
        int rr = wy * 64 + mt * 16 + quad * 4;
        uint32_t ua = pkbf(acc[mt][nt][0], acc[mt][nt][1]);
        uint32_t ub = pkbf(acc[mt][nt][2], acc[mt][nt][3]);
        T[(rr + 0) * 130 + cc] = (u16)ua;
        T[(rr + 1) * 130 + cc] = (u16)(ua >> 16);
        T[(rr + 2) * 130 + cc] = (u16)ub;
        T[(rr + 3) * 130 + cc] = (u16)(ub >> 16);
      }
    __syncthreads();
    const int h0 = blockIdx.x * 2, bb = m0 >> 11, lb = m0 & 2047;
    #pragma unroll
    for (int i = 0; i < 8; ++i) {
      int s = t + i * 256;           // 0..2047 = 128 cols x 16 l-chunks
      int c = s >> 4, l0 = (s & 15) * 8;
      bf16x8 p;
      #pragma unroll
      for (int j = 0; j < 8; ++j) p[j] = (short)T[(l0 + j) * 130 + c];
      *(bf16x8*)(Vt + (long)(bb * 16 + h0 + (c >> 6)) * 131072 +
                 (long)(c & 63) * 2048 + lb + l0) = p;
    }
  }
}

// ---- out-proj GEMM: 128x64 tile, grid (16,32), async16, f32 out + bias ----
// (R8-verbatim)
__global__ __launch_bounds__(256) void k_gemm_out(const u16* __restrict__ A,
                                                  const u16* __restrict__ Bt,
                                                  float* __restrict__ C,
                                                  const float* __restrict__ bias) {
  __shared__ __align__(16) u16 As[128 * 32];
  __shared__ __align__(16) u16 Bs[64 * 32];
  const int t = threadIdx.x, lane = t & 63, quad = lane >> 4, l16 = lane & 15;
  const int wave = t >> 6;
  const int m0 = blockIdx.y * 128, n0 = blockIdx.x * 64;
  const int wbase = t & 192;
  f32x4 acc[2][4] = {};
  for (int k0 = 0; k0 < 1024; k0 += 32) {
    __syncthreads();
    #pragma unroll
    for (int i = 0; i < 2; ++i) {
      int sb = i * 256 + wbase;
      int s = sb + lane;
      int row = s >> 2, c = s & 3;
      async16(As + sb * 8, A + (long)(m0 + row) * 1024 + k0 + c * 8);
    }
    {
      int s = t;
      int row = s >> 2, c = s & 3;
      async16(Bs + wbase * 8, Bt + (long)(n0 + row) * 1024 + k0 + c * 8);
    }
    __syncthreads();
    bf16x8 af[2], bfr[4];
    #pragma unroll
    for (int mt = 0; mt < 2; ++mt)
      af[mt] = *(const bf16x8*)(As + (wave * 32 + mt * 16 + l16) * 32 + quad * 8);
    #pragma unroll
    for (int nt = 0; nt < 4; ++nt)
      bfr[nt] = *(const bf16x8*)(Bs + (nt * 16 + l16) * 32 + quad * 8);
    #pragma unroll
    for (int mt = 0; mt < 2; ++mt)
      #pragma unroll
      for (int nt = 0; nt < 4; ++nt)
        acc[mt][nt] = __builtin_amdgcn_mfma_f32_16x16x32_bf16(af[mt], bfr[nt], acc[mt][nt], 0, 0, 0);
  }
  #pragma unroll
  for (int mt = 0; mt < 2; ++mt)
    #pragma unroll
    for (int nt = 0; nt < 4; ++nt) {
      int col = n0 + nt * 16 + l16;
      #pragma unroll
      for (int r = 0; r < 4; ++r) {
        int row = m0 + wave * 32 + mt * 16 + quad * 4 + r;
        C[(long)row * 1024 + col] = acc[mt][nt][r] + bias[col];
      }
    }
}

// ------- flash attention (R4 schedule, q-tile 256, kv-split wave pairs) ----
// 512 threads, q-tile 256, grid 256 = 1 block/CU. Loop/barrier schedule is
// the proven R4 winner (do NOT reschedule). R2 LDS accounting: kf/vf reads
// were 128KB of 208KB per kt (every wave read the FULL 64-kv K/V tile).
// THIS round: wave w owns q-rows (w>>1)*64..+63 (64 q) and kv-HALF (w&1)
// (32 kv). Same 32 MFMA/wave/kt, but kf+vf = 8 b128/wave -> 64KB/kt (-50%).
// Unnormalized exp2 softmax (no running max) => partial (O,l) over kv-halves
// are directly addable: one LDS merge after the loop (2 rounds through dead
// P buffer). New P layout: per-wave 64x32 in qs (exactly 32KB/8 waves),
// chunk-XOR swizzle (chunk' = chunk ^ (row&3)) -> conflict-free b64 stores
// AND b128 reads (uniform banks, derived).
__global__ __launch_bounds__(512, 2) void k_flash(const u16* __restrict__ Qp,
                                                  const u16* __restrict__ Kp,
                                                  const u16* __restrict__ Vt,
                                                  u16* __restrict__ ctx) {
  __shared__ __align__(16) u16 qs[16384];      // 32KB: Q stage -> P (8 x 64x32) -> O-merge
  __shared__ __align__(16) u16 ks[64 * 72];    // K tile, padded rows
  __shared__ __align__(16) u16 vs[64 * 72];    // V^T tile, padded rows
  __shared__ __align__(16) float lsb[1024];    // 4KB l merge (4 pairs x 64 lanes x 4)
  const int t = threadIdx.x, lane = t & 63, quad = lane >> 4, l16 = lane & 15;
  const int wave = t >> 6;                      // 0..7
  const int qg = wave >> 1, kvh = wave & 1;     // q-group 0..3, kv-half 0..1
  const int bh = blockIdx.x & 31, b = bh >> 4, h = bh & 15;
  const int q0 = (blockIdx.x >> 5) * 256;
  const long gkbase = (long)b * 2097152 + h * 64;
  const long gvbase = (long)bh * 131072;
  const int srow = t >> 3, sc = t & 7;          // staging: row 0..63, 16B chunk 0..7

  // ---- startup: Q via async16 (XOR swizzle), K/V tile 0 via regs ----
  {
    long gq = (long)(b * 2048 + q0) * 1024 + h * 64;
    #pragma unroll
    for (int i = 0; i < 4; ++i) {
      int s = i * 512 + t;
      int row = s >> 3, pos = s & 7, c = pos ^ (row & 7);
      async16(qs + (long)s * 8, Qp + gq + (long)row * 1024 + c * 8);
    }
  }
  bf16x8 kreg = *(const bf16x8*)(Kp + gkbase + (long)srow * 1024 + sc * 8);
  bf16x8 vreg = *(const bf16x8*)(Vt + gvbase + (long)srow * 2048 + sc * 8);
  __syncthreads();  // Q visible

  bf16x8 qf[4][2];
  #pragma unroll
  for (int msub = 0; msub < 4; ++msub)
    #pragma unroll
    for (int kh = 0; kh < 2; ++kh) {
      int m = qg * 64 + msub * 16 + l16;
      int pos = (kh * 4 + quad) ^ (m & 7);
      qf[msub][kh] = *(const bf16x8*)(qs + m * 64 + pos * 8);
    }
  *(bf16x8*)(ks + srow * 72 + sc * 8) = kreg;
  *(bf16x8*)(vs + srow * 72 + sc * 8) = vreg;
  __syncthreads();  // K/V tile 0 visible; all qf reads drained -> qs safe as P

  u16* pw = qs + wave * 2048;      // per-wave P: 64 q-rows x 32 kv, chunk-XOR
  const int pxor = l16 & 3;

  float ls[4] = {};
  f32x4 o[4][4] = {};

  for (int kt = 0; kt < 32; ++kt) {
    // register prefetch of next K/V tile (in flight across this compute phase)
    if (kt < 31) {
      int kv0 = (kt + 1) * 64;
      kreg = *(const bf16x8*)(Kp + gkbase + (long)(kv0 + srow) * 1024 + sc * 8);
      vreg = *(const bf16x8*)(Vt + gvbase + kv0 + (long)srow * 2048 + sc * 8);
    }

    // K (own kv-half rows) and V^T (all d rows, own kv-half cols) fragments
    bf16x8 kf[2][2], vf[4];
    #pragma unroll
    for (int nt = 0; nt < 2; ++nt)
      #pragma unroll
      for (int kh = 0; kh < 2; ++kh)
        kf[nt][kh] = *(const bf16x8*)(ks + (kvh * 32 + nt * 16 + l16) * 72 + kh * 32 + quad * 8);
    #pragma unroll
    for (int dt = 0; dt < 4; ++dt)
      vf[dt] = *(const bf16x8*)(vs + (dt * 16 + l16) * 72 + kvh * 32 + quad * 8);

    #pragma unroll
    for (int msub = 0; msub < 4; ++msub) {
      // S^T(32x16) = K @ Q^T over this wave's kv-half; lane holds
      // S[q = qg*64+msub*16+l16][kv_local = nt*16+quad*4+r]. p = exp2(s).
      #pragma unroll
      for (int nt = 0; nt < 2; ++nt) {
        f32x4 a = {};
        #pragma unroll
        for (int kh = 0; kh < 2; ++kh)
          a = __builtin_amdgcn_mfma_f32_16x16x32_bf16(kf[nt][kh], qf[msub][kh], a, 0, 0, 0);
        float e0 = __builtin_amdgcn_exp2f(a[0]);
        float e1 = __builtin_amdgcn_exp2f(a[1]);
        float e2 = __builtin_amdgcn_exp2f(a[2]);
        float e3 = __builtin_amdgcn_exp2f(a[3]);
        ls[msub] += (e0 + e1) + (e2 + e3);
        uint2 w;
        w.x = pkbf(e0, e1);
        w.y = pkbf(e2, e3);
        int cp = (nt * 2 + (quad >> 1)) ^ pxor;   // swizzled 8-elem chunk
        *(uint2*)(pw + (msub * 16 + l16) * 32 + cp * 8 + (quad & 1) * 4) = w;
      }
      // O(16q x 64d) += P(16q x 32kv) @ V(32kv x 64d): single K=32 step
      bf16x8 pa = *(const bf16x8*)(pw + (msub * 16 + l16) * 32 + (quad ^ pxor) * 8);
      #pragma unroll
      for (int dt = 0; dt < 4; ++dt)
        o[msub][dt] = __builtin_amdgcn_mfma_f32_16x16x32_bf16(pa, vf[dt], o[msub][dt], 0, 0, 0);
    }

    __syncthreads();  // all waves done reading ks/vs (and prefetch drained)
    if (kt < 31) {
      *(bf16x8*)(ks + srow * 72 + sc * 8) = kreg;
      *(bf16x8*)(vs + srow * 72 + sc * 8) = vreg;
    }
    __syncthreads();  // next tile visible
  }

  // ---- kv-half merge: quad-reduce l, then pair (2k,2k+1) add O and l ----
  #pragma unroll
  for (int m = 0; m < 4; ++m) {
    ls[m] += __shfl_xor(ls[m], 16);
    ls[m] += __shfl_xor(ls[m], 32);   // lane now holds l_half for q = m*16+l16
  }
  f32x4* mb = (f32x4*)qs;             // 2048 f32x4 = 32KB (P dead)
  f32x4* lb = (f32x4*)lsb;
  for (int r = 0; r < 2; ++r) {       // round r merges pairs {2r, 2r+1}
    __syncthreads();
    if ((wave & 1) && (qg >> 1) == r) {
      f32x4* dst = mb + (qg & 1) * 1024 + lane;
      #pragma unroll
      for (int m = 0; m < 4; ++m)
        #pragma unroll
        for (int d = 0; d < 4; ++d)
          dst[(m * 4 + d) * 64] = o[m][d];
      f32x4 lp = {ls[0], ls[1], ls[2], ls[3]};
      lb[qg * 64 + lane] = lp;
    }
    __syncthreads();
    if (!(wave & 1) && (qg >> 1) == r) {
      f32x4* src = mb + (qg & 1) * 1024 + lane;
      #pragma unroll
      for (int m = 0; m < 4; ++m)
        #pragma unroll
        for (int d = 0; d < 4; ++d)
          o[m][d] += src[(m * 4 + d) * 64];
      f32x4 lp = lb[qg * 64 + lane];
      ls[0] += lp[0]; ls[1] += lp[1]; ls[2] += lp[2]; ls[3] += lp[3];
    }
  }

  // even waves: normalize + write 64 q-rows each
  if (!(wave & 1)) {
    #pragma unroll
    for (int m = 0; m < 4; ++m) {
      float linv = 1.0f / ls[m];               // valid for q = m*16+l16
      float li0 = __shfl(linv, quad * 4 + 0);
      float li1 = __shfl(linv, quad * 4 + 1);
      float li2 = __shfl(linv, quad * 4 + 2);
      float li3 = __shfl(linv, quad * 4 + 3);
      #pragma unroll
      for (int dt = 0; dt < 4; ++dt) {
        int q = q0 + qg * 64 + m * 16 + quad * 4;
        long idx = (long)(b * 2048 + q) * 1024 + h * 64 + dt * 16 + l16;
        uint32_t ua = pkbf(o[m][dt][0] * li0, o[m][dt][1] * li1);
        uint32_t ub = pkbf(o[m][dt][2] * li2, o[m][dt][3] * li3);
        ctx[idx]        = (u16)ua;
        ctx[idx + 1024] = (u16)(ua >> 16);
        ctx[idx + 2048] = (u16)ub;
        ctx[idx + 3072] = (u16)(ub >> 16);
      }
    }
  }
}

extern "C" void kernel_launch(void* const* d_in, const int* in_sizes, int n_in,
                              void* d_out, int out_size, void* d_ws, size_t ws_size,
                              hipStream_t stream) {
  const float* query = (const float*)d_in[0];
  const float* key   = (const float*)d_in[1];
  const float* value = (const float*)d_in[2];
  const float* Wq    = (const float*)d_in[3];
  const float* Wk    = (const float*)d_in[4];
  const float* Wv    = (const float*)d_in[5];
  const float* out_w = (const float*)d_in[6];
  const float* out_b = (const float*)d_in[7];
  // d_in[8] = coupling: unused — per-head scalar bias is softmax-invariant.
  float* out = (float*)d_out;

  char* ws = (char*)d_ws;
  size_t off = 0;
  auto alloc = [&](size_t bytes) {
    void* p = ws + off;
    off += (bytes + 255) & ~(size_t)255;
    return p;
  };
  // qb,kb,vb contiguous (k_prep cast z-stride); wtq..wtv contiguous
  // (k_prep transpose z-stride); Qp,Kp contiguous (k_gemm_qkv z<2 stride).
  u16* qb  = (u16*)alloc(4096L * 1024 * 2);
  u16* kb  = (u16*)alloc(4096L * 1024 * 2);
  u16* vb  = (u16*)alloc(4096L * 1024 * 2);
  u16* wtq = (u16*)alloc(1024L * 1024 * 2);
  u16* wtk = (u16*)alloc(1024L * 1024 * 2);
  u16* wtv = (u16*)alloc(1024L * 1024 * 2);
  u16* wto = (u16*)alloc(1024L * 1024 * 2);
  u16* Qp  = (u16*)alloc(4096L * 1024 * 2);
  u16* Kp  = (u16*)alloc(4096L * 1024 * 2);
  u16* Vtb = (u16*)alloc(4096L * 1024 * 2);
  u16* ctx = qb;  // reuse: query-bf16 dead after Q projection
  (void)kb; (void)vb; (void)wtk; (void)wtv; (void)Kp;

  // fused pre-pass: input casts + all weight transposes in one launch
  k_prep<<<13312, 256, 0, stream>>>(Ptr3{query, key, value}, qb,
                                    Ptr3{Wq, Wk, Wv}, out_w, wtq, wto);

  // fused Q,K,V projections; z==2 writes Vt[bh][d][l] directly
  k_gemm_qkv<<<dim3(8, 32, 3), 256, 0, stream>>>(qb, wtq, Qp, Vtb, QSCALE);

  // attention: grid 256 = 8 q-tiles x 32 bh, bh in low 5 bits for XCD affinity
  k_flash<<<256, 512, 0, stream>>>(Qp, Kp, Vtb, ctx);

  // output projection + bias -> f32
  k_gemm_out<<<dim3(16, 32), 256, 0, stream>>>(ctx, wto, out, out_b);
}